// Round 6
// baseline (390.770 us; speedup 1.0000x reference)
//
#include <hip/hip_runtime.h>

// Problem constants (fixed by the reference's setup_inputs)
#define NN   100000      // nodes
#define EE   1600000     // num_edge
#define EROW 4800000     // edge_index row length (3*NUM_EDGE)

typedef _Float16 half8 __attribute__((ext_vector_type(8)));
typedef _Float16 half4 __attribute__((ext_vector_type(4)));
typedef float    f32x4 __attribute__((ext_vector_type(4)));

__device__ __forceinline__ float4 ld4(const float* p){ return *(const float4*)p; }

// Split fp32 -> (hi fp16) + (lo fp16, scaled by 2048). Packed lo16=hi, hi16=lo.
__device__ __forceinline__ unsigned splitf(float v) {
    _Float16 h = (_Float16)v;
    float r = v - (float)h;
    _Float16 l = (_Float16)(r * 2048.0f);
    union { _Float16 f; unsigned short u; } uh, ul;
    uh.f = h; ul.f = l;
    return (unsigned)uh.u | ((unsigned)ul.u << 16);
}

// Async global->LDS DMA, 16 B per lane. LDS dest = wave-uniform base + lane*16.
__device__ __forceinline__ void dma16(const void* g, void* l) {
    __builtin_amdgcn_global_load_lds(
        (const __attribute__((address_space(1))) unsigned*)((size_t)g),
        (__attribute__((address_space(3))) unsigned*)((size_t)l),
        16, 0, 0);
}

// ---------------------------------------------------------------------------
// Weight prep: split W_lin (256x256), W_lin2 (128x256), repacked W_fc1
// (128x128: row j = W_fc1[j&63][(j>>6)*128 ..]) into interleaved half2 planes.
// ---------------------------------------------------------------------------
__global__ __launch_bounds__(256)
void prep_w(const float* __restrict__ W1, const float* __restrict__ W2,
            const float* __restrict__ W3, unsigned* __restrict__ o1,
            unsigned* __restrict__ o2, unsigned* __restrict__ o3)
{
    int idx = blockIdx.x * 256 + threadIdx.x;   // 448 blocks = 114688 threads
    if (idx < 65536) {
        o1[idx] = splitf(W1[idx]);
    } else if (idx < 98304) {
        int i = idx - 65536;
        o2[i] = splitf(W2[i]);
    } else {
        int i = idx - 98304;
        int j = i >> 7, k = i & 127;
        o3[i] = splitf(W3[(j & 63) * 256 + (j >> 6) * 128 + k]);
    }
}

// ---------------------------------------------------------------------------
// MFMA split-fp16 GEMM: C[M x No] = A[M x K] @ B[No x K]^T (+epilogue).
//
// R6 OCCUPANCY RETILE. R2-R5 invariants (Occ 19%, HBM 2TB/s, Mfma 15% across
// three staging schemes) showed the bottleneck is 2 waves/SIMD: acc 128 regs
// (aH+aM) + 124 arch = ~252/wave caps occupancy, and 2 waves can't hide
// 500-900cy staging latency. New shape: block tile 128x64, 4 waves (grid
// 4x1), wave tile 32x64 -> acc 64 regs, A-frags 16, B streamed per-j (8).
// __launch_bounds__(256,3) targets 3 waves/SIMD; LDS 48KB -> 3 blocks/CU.
//
// GEMM2's row-normalize needed all 128 cols (block now owns 64), so the
// normalization MOVES INTO GEMM3: p = (W3 . m)/||m||, with ||m|| computed
// from GEMM3's own staged A-tile (full row, K=128), reconstructed hi+lo/2048.
//
// Staging (R5-verified): global_load_lds DMA of raw tiles, double-buffered,
// ONE __syncthreads per K-step. LDS XOR involution: 16B chunk c of row r
// holds global chunk c^(r&7); DMA pre-swizzles the global source with
// col16 = (l&7)^(l>>3); reads XOR chunk with (r&7).
//
// SRCA 0: A = trace fp32 (2-plane, split on read). 1: interleaved plane.
// EPI  0: relu, store split plane.   1: plain split store (no relu).
//      2: /= row-norm, += b_fc1 (blockIdx.y==0 cols), store fp32 + fp16.
// ---------------------------------------------------------------------------
template<int SRCA, int EPI, int K>
__global__ __launch_bounds__(256, 3)
void gemm_mfma(const void* __restrict__ Asrc, const unsigned* __restrict__ Bw,
               const float* __restrict__ bias, unsigned* __restrict__ outS,
               float* __restrict__ outF, unsigned short* __restrict__ outH,
               int M, int No)
{
    // A: 128 rows x 32 dw (16KB); B: 64 rows x 32 dw (8KB); double-buffered.
    __shared__ __align__(16) unsigned bufA[2][128 * 32];
    __shared__ __align__(16) unsigned bufB[2][64 * 32];
    __shared__ float sqv[128];         // EPI==2 row-ssq exchange

    const int t     = threadIdx.x;
    const int w     = t >> 6;          // wave id 0..3 = wave m index
    const int lane  = t & 63;
    const int lm    = lane & 15;
    const int q     = lane >> 4;
    const int mBase = blockIdx.x * 128;
    const int nBase = blockIdx.y * 64;

    // DMA source swizzle: lane's linear LDS slot (l&7) gets global chunk
    // (l&7)^(l>>3); row&7 == l>>3 for every staged chunk.
    const int col16 = (lane & 7) ^ (lane >> 3);

    f32x4 aH[2][4], aM[2][4];
#pragma unroll
    for (int i = 0; i < 2; ++i)
#pragma unroll
        for (int j = 0; j < 4; ++j) {
            aH[i][j] = (f32x4){0.f, 0.f, 0.f, 0.f};
            aM[i][j] = (f32x4){0.f, 0.f, 0.f, 0.f};
        }

    float ssq[2] = {0.f, 0.f};         // EPI==2: row sum-of-squares partials

    auto stage = [&](int sb, int kt) {
#pragma unroll
        for (int c = 0; c < 4; ++c) {  // A: wave covers 32 rows
            const int row = w * 32 + c * 8 + (lane >> 3);
            unsigned* ldsA = &bufA[sb][w * 1024 + c * 256];
            int rgA = mBase + row; rgA = rgA < M ? rgA : M - 1;
            if (SRCA == 0) {
                const int kg = kt * 32;
                const float* gA = (const float*)Asrc
                    + (size_t)(kg >> 7) * ((size_t)NN * 128)
                    + (size_t)rgA * 128 + (kg & 127) + col16 * 4;
                dma16(gA, ldsA);
            } else {
                const unsigned* gA = (const unsigned*)Asrc
                    + (size_t)rgA * K + kt * 32 + col16 * 4;
                dma16(gA, ldsA);
            }
        }
#pragma unroll
        for (int c = 0; c < 2; ++c) {  // B: wave covers 16 rows
            const int row = w * 16 + c * 8 + (lane >> 3);
            unsigned* ldsB = &bufB[sb][w * 512 + c * 256];
            const unsigned* gB = Bw + (size_t)(nBase + row) * K + kt * 32 + col16 * 4;
            dma16(gB, ldsB);
        }
    };

    union HL { uint4 u; half8 h; };

    constexpr int NK = K / 32;
    stage(0, 0);
    __syncthreads();   // drains vmcnt(0): tile 0 resident

#pragma unroll 2
    for (int kt = 0; kt < NK; ++kt) {
        const int b = kt & 1;
        if (kt + 1 < NK) stage(b ^ 1, kt + 1);   // in flight across compute

        // ---- A fragments: swizzled raw read + split/deinterleave ----
        half8 fAh[2], fAl[2];
#pragma unroll
        for (int i = 0; i < 2; ++i) {
            const int r = w * 32 + i * 16 + lm;
            const int x = lm & 7;
            const unsigned* p0p = &bufA[b][r * 32 + (((2 * q) ^ x) << 2)];
            const unsigned* p1p = &bufA[b][r * 32 + ((((2 * q) | 1) ^ x) << 2)];
            HL H, L;
            if (SRCA == 0) {
                float4 f0 = *(const float4*)p0p;
                float4 f1 = *(const float4*)p1p;
                unsigned p0 = splitf(f0.x), p1 = splitf(f0.y);
                unsigned p2 = splitf(f0.z), p3 = splitf(f0.w);
                unsigned p4 = splitf(f1.x), p5 = splitf(f1.y);
                unsigned p6 = splitf(f1.z), p7 = splitf(f1.w);
                H.u.x = (p0 & 0xffffu) | (p1 << 16);
                H.u.y = (p2 & 0xffffu) | (p3 << 16);
                H.u.z = (p4 & 0xffffu) | (p5 << 16);
                H.u.w = (p6 & 0xffffu) | (p7 << 16);
                L.u.x = (p0 >> 16) | (p1 & 0xffff0000u);
                L.u.y = (p2 >> 16) | (p3 & 0xffff0000u);
                L.u.z = (p4 >> 16) | (p5 & 0xffff0000u);
                L.u.w = (p6 >> 16) | (p7 & 0xffff0000u);
            } else {
                uint4 u0 = *(const uint4*)p0p;
                uint4 u1 = *(const uint4*)p1p;
                H.u.x = (u0.x & 0xffffu) | (u0.y << 16);
                H.u.y = (u0.z & 0xffffu) | (u0.w << 16);
                H.u.z = (u1.x & 0xffffu) | (u1.y << 16);
                H.u.w = (u1.z & 0xffffu) | (u1.w << 16);
                L.u.x = (u0.x >> 16) | (u0.y & 0xffff0000u);
                L.u.y = (u0.z >> 16) | (u0.w & 0xffff0000u);
                L.u.z = (u1.x >> 16) | (u1.y & 0xffff0000u);
                L.u.w = (u1.z >> 16) | (u1.w & 0xffff0000u);
            }
            fAh[i] = H.h;
            fAl[i] = L.h;
            if (EPI == 2) {            // row-ssq from reconstructed values
#pragma unroll
                for (int e = 0; e < 8; ++e) {
                    float v = (float)fAh[i][e] + (float)fAl[i][e] * (1.0f / 2048.0f);
                    ssq[i] = fmaf(v, v, ssq[i]);
                }
            }
        }

        // ---- B streamed per-j + MFMA (6 MFMAs per B-frag) ----
        __builtin_amdgcn_s_setprio(1);
#pragma unroll
        for (int j = 0; j < 4; ++j) {
            const int rB = j * 16 + lm;
            const int x = lm & 7;
            uint4 u0 = *(const uint4*)&bufB[b][rB * 32 + (((2 * q) ^ x) << 2)];
            uint4 u1 = *(const uint4*)&bufB[b][rB * 32 + ((((2 * q) | 1) ^ x) << 2)];
            HL H, L;
            H.u.x = (u0.x & 0xffffu) | (u0.y << 16);
            H.u.y = (u0.z & 0xffffu) | (u0.w << 16);
            H.u.z = (u1.x & 0xffffu) | (u1.y << 16);
            H.u.w = (u1.z & 0xffffu) | (u1.w << 16);
            L.u.x = (u0.x >> 16) | (u0.y & 0xffff0000u);
            L.u.y = (u0.z >> 16) | (u0.w & 0xffff0000u);
            L.u.z = (u1.x >> 16) | (u1.y & 0xffff0000u);
            L.u.w = (u1.z >> 16) | (u1.w & 0xffff0000u);
#pragma unroll
            for (int i = 0; i < 2; ++i) {
                aH[i][j] = __builtin_amdgcn_mfma_f32_16x16x32_f16(fAh[i], H.h, aH[i][j], 0, 0, 0);
                aM[i][j] = __builtin_amdgcn_mfma_f32_16x16x32_f16(fAh[i], L.h, aM[i][j], 0, 0, 0);
                aM[i][j] = __builtin_amdgcn_mfma_f32_16x16x32_f16(fAl[i], H.h, aM[i][j], 0, 0, 0);
            }
        }
        __builtin_amdgcn_s_setprio(0);

        // Implicit vmcnt(0)+lgkmcnt(0) drain + barrier: next tile resident,
        // and buf[b] reads complete -> safe to overwrite next iteration.
        if (kt + 1 < NK) __syncthreads();
    }

    // Combine split accumulators: C = hi + mid/2048
    const float cM = 1.0f / 2048.0f;
#pragma unroll
    for (int i = 0; i < 2; ++i)
#pragma unroll
        for (int j = 0; j < 4; ++j)
            aH[i][j] = aH[i][j] + aM[i][j] * cM;

    if (EPI == 2) {
        // Reduce ssq over the 4 q-lanes (bits 4,5 of lane), publish per row.
#pragma unroll
        for (int i = 0; i < 2; ++i) {
            float s = ssq[i];
            s += __shfl_xor(s, 16);
            s += __shfl_xor(s, 32);
            if (q == 0) sqv[w * 32 + i * 16 + lm] = s;
        }
        __syncthreads();
    }

    float bj[4] = {0.f, 0.f, 0.f, 0.f};
    if (EPI == 2 && nBase == 0 && bias) {
#pragma unroll
        for (int j = 0; j < 4; ++j) bj[j] = bias[j * 16 + lm];
    }

#pragma unroll
    for (int i = 0; i < 2; ++i)
#pragma unroll
        for (int r = 0; r < 4; ++r) {
            const int m = mBase + w * 32 + i * 16 + q * 4 + r;
            if (m < M) {
                float nm = 1.f;
                if (EPI == 2)
                    nm = fmaxf(sqrtf(sqv[w * 32 + i * 16 + q * 4 + r]), 1e-12f);
#pragma unroll
                for (int j = 0; j < 4; ++j) {
                    const int c = nBase + j * 16 + lm;
                    float v = aH[i][j][r];
                    if (EPI == 0) { v = fmaxf(v, 0.f); outS[(size_t)m * No + c] = splitf(v); }
                    if (EPI == 1) { outS[(size_t)m * No + c] = splitf(v); }
                    if (EPI == 2) {
                        v = v / nm + bj[j];
                        outF[(size_t)m * No + c] = v;
                        union { _Float16 f; unsigned short u; } cv; cv.f = (_Float16)v;
                        outH[(size_t)m * No + c] = cv.u;
                    }
                }
            }
        }
}

// ---------------------------------------------------------------------------
// Edge kernel: 128 edges/block, 16 lanes/edge, 8 edges/lane-group.
// Fast path gathers the fp16 p-table (8 B/lane per edge-half). The decision
// only needs the SIGN of the score gap: gap = sum relu(a+c)*(w0-w1) + dB + dg,
// so we accumulate ONE dot with dk = w0-w1 and butterfly-reduce 2 values
// (sc, eb). Certified bound: |fast gap - exact gap| <=
// 2^-10 * sum |dk|*(|a|+|c|) + 2e-5 slack; if |gap| <= bound, re-gather fp32
// and recompute exactly (path unchanged — it is the arbiter). Butterfly
// results are bit-identical across lanes -> branch uniform per 16-lane group.
// ---------------------------------------------------------------------------
#define EPB 128
__global__ __launch_bounds__(256, 4)
void edge_k(const unsigned short* __restrict__ pH, const float* __restrict__ p,
            const int* __restrict__ ei, const float* __restrict__ gum,
            const float* __restrict__ W2, const float* __restrict__ b2,
            float* __restrict__ out)
{
    __shared__ int   sidx[EPB];
    __shared__ int   didx[EPB];
    __shared__ float gl[2 * EPB];
    __shared__ float act[EPB];

    const int t  = threadIdx.x;
    const int e0 = blockIdx.x * EPB;

    if (t < EPB) sidx[t] = ei[e0 + t];
    else         didx[t - EPB] = ei[EROW + e0 + (t - EPB)];
    gl[t] = gum[(size_t)e0 * 2 + t];
    __syncthreads();

    const int j   = t & 15;
    const int grp = t >> 4;
    const float4 w0 = ld4(&W2[j * 4]);
    const float4 w1 = ld4(&W2[64 + j * 4]);
    const float4 dk = make_float4(w0.x - w1.x, w0.y - w1.y,
                                  w0.z - w1.z, w0.w - w1.w);
    const float4 dw = make_float4(fabsf(dk.x), fabsf(dk.y),
                                  fabsf(dk.z), fabsf(dk.w));
    const float b20 = b2[0], b21 = b2[1];
    const float dB  = b20 - b21;

    union U8 { uint2 u; half4 h; };
    U8 ua[8], ub[8];
#pragma unroll
    for (int it = 0; it < 8; ++it) {
        const int el = grp * 8 + it;
        ua[it].u = *(const uint2*)&pH[(size_t)sidx[el] * 128 + j * 4];
        ub[it].u = *(const uint2*)&pH[(size_t)didx[el] * 128 + 64 + j * 4];
    }

#pragma unroll
    for (int it = 0; it < 8; ++it) {
        const int el = grp * 8 + it;
        const float a0 = (float)ua[it].h[0], a1 = (float)ua[it].h[1];
        const float a2 = (float)ua[it].h[2], a3 = (float)ua[it].h[3];
        const float c0 = (float)ub[it].h[0], c1 = (float)ub[it].h[1];
        const float c2 = (float)ub[it].h[2], c3 = (float)ub[it].h[3];
        const float r0 = fmaxf(a0 + c0, 0.f);
        const float r1 = fmaxf(a1 + c1, 0.f);
        const float r2 = fmaxf(a2 + c2, 0.f);
        const float r3 = fmaxf(a3 + c3, 0.f);
        float sc = r0 * dk.x + r1 * dk.y + r2 * dk.z + r3 * dk.w;
        float eb = dw.x * (fabsf(a0) + fabsf(c0)) + dw.y * (fabsf(a1) + fabsf(c1))
                 + dw.z * (fabsf(a2) + fabsf(c2)) + dw.w * (fabsf(a3) + fabsf(c3));
#pragma unroll
        for (int off = 1; off < 16; off <<= 1) {
            sc += __shfl_xor(sc, off, 16);
            eb += __shfl_xor(eb, off, 16);
        }
        const float g0 = gl[el * 2], g1 = gl[el * 2 + 1];
        const float gap = sc + dB + (g0 - g1);
        const float bound = eb * 0.0009765625f + 2e-5f;   // 2^-10 * eb + slack
        float av;
        if (fabsf(gap) > bound) {
            av = (gap >= 0.f) ? 1.f : 0.f;
        } else {
            // Exact fp32 recompute (rare; uniform within the 16-lane group).
            const float4 pa = ld4(&p[(size_t)sidx[el] * 128 + j * 4]);
            const float4 pb = ld4(&p[(size_t)didx[el] * 128 + 64 + j * 4]);
            const float q0 = fmaxf(pa.x + pb.x, 0.f);
            const float q1 = fmaxf(pa.y + pb.y, 0.f);
            const float q2 = fmaxf(pa.z + pb.z, 0.f);
            const float q3 = fmaxf(pa.w + pb.w, 0.f);
            float t0 = q0 * w0.x + q1 * w0.y + q2 * w0.z + q3 * w0.w;
            float t1 = q0 * w1.x + q1 * w1.y + q2 * w1.z + q3 * w1.w;
#pragma unroll
            for (int off = 1; off < 16; off <<= 1) {
                t0 += __shfl_xor(t0, off, 16);
                t1 += __shfl_xor(t1, off, 16);
            }
            const float ge = (t0 + b20 + g0) - (t1 + b21 + g1);
            av = (ge >= 0.f) ? 1.f : 0.f;
        }
        if (j == 0) act[el] = av;
    }
    __syncthreads();

    if (t < EPB) {
        const float a = act[t];
        const size_t e = (size_t)e0 + t;
        out[e]                  = a;
        out[EE + e]             = 1.f - a;
        out[2 * (size_t)EE + e] = 1.f - a;
    }
}

// ---------------------------------------------------------------------------
extern "C" void kernel_launch(void* const* d_in, const int* in_sizes, int n_in,
                              void* d_out, int out_size, void* d_ws, size_t ws_size,
                              hipStream_t stream)
{
    const float* trace  = (const float*)d_in[0];   // (2,100000,128)
    const float* W_lin  = (const float*)d_in[1];   // (256,256)
    const float* W_lin2 = (const float*)d_in[2];   // (128,256)
    const float* W_fc1  = (const float*)d_in[3];   // (64,256)
    const float* b_fc1  = (const float*)d_in[4];   // (64,)
    const float* W_fc2  = (const float*)d_in[5];   // (2,64)
    const float* b_fc2  = (const float*)d_in[6];   // (2,)
    const float* gum    = (const float*)d_in[7];   // (1600000,2)
    const int*   ei     = (const int*)  d_in[8];   // (2,4800000)
    float*       out    = (float*)d_out;           // (4800000,)

    // Workspace: h split-plane [NN x 256 dw] at 0 (102.4 MB); m split-plane
    // [NN x 128 dw] (51.2 MB, UNnormalized — GEMM3 divides by row norm);
    // weight planes (459 KB). p (fp32, 51.2 MB) and pH (fp16, 25.6 MB)
    // overlay h's region (h dead after GEMM2). ~154 MB.
    char* ws = (char*)d_ws;
    unsigned*       hpl = (unsigned*)ws;
    unsigned*       mpl = (unsigned*)(ws + (size_t)NN * 256 * 4);
    unsigned*       W1i = (unsigned*)(ws + (size_t)NN * 256 * 4 + (size_t)NN * 128 * 4);
    unsigned*       W2i = W1i + 65536;
    unsigned*       W3i = W2i + 32768;
    float*          p   = (float*)ws;                                  // 51.2 MB
    unsigned short* pH  = (unsigned short*)(ws + (size_t)NN * 128 * 4); // +25.6 MB

    // Split weights into fp16 hi/lo interleaved planes.
    prep_w<<<448, 256, 0, stream>>>(W_lin, W_lin2, W_fc1, W1i, W2i, W3i);

    const int mB = (NN + 127) / 128;   // 782

    // h = relu(x @ W_lin^T), stored split
    gemm_mfma<0, 0, 256><<<dim3(mB, 4), 256, 0, stream>>>(trace, W1i, nullptr, hpl, nullptr, nullptr, NN, 256);
    // m = h @ W_lin2^T (unnormalized), stored split
    gemm_mfma<1, 1, 256><<<dim3(mB, 2), 256, 0, stream>>>(hpl, W2i, nullptr, mpl, nullptr, nullptr, NN, 128);
    // p[n] = [W_fc1_left @ m_n / ||m_n|| + b_fc1 | W_fc1_right @ m_n / ||m_n||]
    gemm_mfma<1, 2, 128><<<dim3(mB, 2), 256, 0, stream>>>(mpl, W3i, b_fc1, nullptr, p, pH, NN, 128);
    // per-edge score + hard mask (fp16 fast path, certified fp32 fallback)
    edge_k<<<EE / EPB, 256, 0, stream>>>(pH, p, ei, gum, W_fc2, b_fc2, out);
}

// Round 8
// 364.860 us; speedup vs baseline: 1.0710x; 1.0710x over previous
//
#include <hip/hip_runtime.h>

// Problem constants (fixed by the reference's setup_inputs)
#define NN   100000      // nodes
#define EE   1600000     // num_edge
#define EROW 4800000     // edge_index row length (3*NUM_EDGE)

typedef _Float16 half8 __attribute__((ext_vector_type(8)));
typedef _Float16 half4 __attribute__((ext_vector_type(4)));
typedef float    f32x4 __attribute__((ext_vector_type(4)));

__device__ __forceinline__ float4 ld4(const float* p){ return *(const float4*)p; }

// Split fp32 -> (hi fp16) + (lo fp16, scaled by 2048). Packed lo16=hi, hi16=lo.
__device__ __forceinline__ unsigned splitf(float v) {
    _Float16 h = (_Float16)v;
    float r = v - (float)h;
    _Float16 l = (_Float16)(r * 2048.0f);
    union { _Float16 f; unsigned short u; } uh, ul;
    uh.f = h; ul.f = l;
    return (unsigned)uh.u | ((unsigned)ul.u << 16);
}

// Async global->LDS DMA, 16 B per lane. LDS dest = wave-uniform base + lane*16.
__device__ __forceinline__ void dma16(const void* g, void* l) {
    __builtin_amdgcn_global_load_lds(
        (const __attribute__((address_space(1))) unsigned*)((size_t)g),
        (__attribute__((address_space(3))) unsigned*)((size_t)l),
        16, 0, 0);
}

// ---------------------------------------------------------------------------
// Weight prep: split W_lin (256x256), W_lin2 (128x256), repacked W_fc1
// (128x128: row j = W_fc1[j&63][(j>>6)*128 ..]) into interleaved half2 planes.
// ---------------------------------------------------------------------------
__global__ __launch_bounds__(256)
void prep_w(const float* __restrict__ W1, const float* __restrict__ W2,
            const float* __restrict__ W3, unsigned* __restrict__ o1,
            unsigned* __restrict__ o2, unsigned* __restrict__ o3)
{
    int idx = blockIdx.x * 256 + threadIdx.x;   // 448 blocks = 114688 threads
    if (idx < 65536) {
        o1[idx] = splitf(W1[idx]);
    } else if (idx < 98304) {
        int i = idx - 65536;
        o2[i] = splitf(W2[i]);
    } else {
        int i = idx - 98304;
        int j = i >> 7, k = i & 127;
        o3[i] = splitf(W3[(j & 63) * 256 + (j >> 6) * 128 + k]);
    }
}

// ---------------------------------------------------------------------------
// GEMM1 (R5-verified structure): C[M x No] = A[M x K] @ B[No x K]^T, relu,
// split-store. 256 thr = 4 waves 2x2, wave tile 64x64. DMA staging of raw
// tiles, double-buffered, ONE __syncthreads per K-step. LDS XOR involution:
// chunk c of row r holds global chunk c^(r&7); DMA pre-swizzles the global
// source with col16 = (l&7)^(l>>3); reads XOR the chunk index with (r&7).
// SRCA 0: A = trace fp32 (2-plane, split on read). 1: interleaved plane.
// ---------------------------------------------------------------------------
template<int SRCA, int K>
__global__ __launch_bounds__(256, 2)
void gemm_mfma(const void* __restrict__ Asrc, const unsigned* __restrict__ Bw,
               unsigned* __restrict__ outS, int M, int No)
{
    __shared__ __align__(16) unsigned bufA[2][128 * 32];
    __shared__ __align__(16) unsigned bufB[2][128 * 32];

    const int t     = threadIdx.x;
    const int w     = t >> 6;
    const int wm    = w >> 1;
    const int wn    = w & 1;
    const int lane  = t & 63;
    const int lm    = lane & 15;
    const int q     = lane >> 4;
    const int mBase = blockIdx.x * 128;
    const int nBase = blockIdx.y * 128;

    const int col16 = (lane & 7) ^ (lane >> 3);

    f32x4 aH[4][4], aM[4][4];
#pragma unroll
    for (int i = 0; i < 4; ++i)
#pragma unroll
        for (int j = 0; j < 4; ++j) {
            aH[i][j] = (f32x4){0.f, 0.f, 0.f, 0.f};
            aM[i][j] = (f32x4){0.f, 0.f, 0.f, 0.f};
        }

    auto stage = [&](int sb, int kt) {
#pragma unroll
        for (int c = 0; c < 4; ++c) {
            const int row = w * 32 + c * 8 + (lane >> 3);
            unsigned* ldsA = &bufA[sb][w * 1024 + c * 256];
            unsigned* ldsB = &bufB[sb][w * 1024 + c * 256];
            int rgA = mBase + row; rgA = rgA < M ? rgA : M - 1;
            if (SRCA == 0) {
                const int kg = kt * 32;
                const float* gA = (const float*)Asrc
                    + (size_t)(kg >> 7) * ((size_t)NN * 128)
                    + (size_t)rgA * 128 + (kg & 127) + col16 * 4;
                dma16(gA, ldsA);
            } else {
                const unsigned* gA = (const unsigned*)Asrc
                    + (size_t)rgA * K + kt * 32 + col16 * 4;
                dma16(gA, ldsA);
            }
            const unsigned* gB = Bw + (size_t)(nBase + row) * K + kt * 32 + col16 * 4;
            dma16(gB, ldsB);
        }
    };

    union HL { uint4 u; half8 h; };

    constexpr int NK = K / 32;
    stage(0, 0);
    __syncthreads();

#pragma unroll 2
    for (int kt = 0; kt < NK; ++kt) {
        const int b = kt & 1;
        if (kt + 1 < NK) stage(b ^ 1, kt + 1);

        half8 fAh[4], fAl[4], fBh[4], fBl[4];

#pragma unroll
        for (int i = 0; i < 4; ++i) {
            const int r = wm * 64 + i * 16 + lm;
            const int x = r & 7;
            const unsigned* p0p = &bufA[b][r * 32 + (((2 * q) ^ x) << 2)];
            const unsigned* p1p = &bufA[b][r * 32 + ((((2 * q) | 1) ^ x) << 2)];
            HL H, L;
            if (SRCA == 0) {
                float4 f0 = *(const float4*)p0p;
                float4 f1 = *(const float4*)p1p;
                unsigned p0 = splitf(f0.x), p1 = splitf(f0.y);
                unsigned p2 = splitf(f0.z), p3 = splitf(f0.w);
                unsigned p4 = splitf(f1.x), p5 = splitf(f1.y);
                unsigned p6 = splitf(f1.z), p7 = splitf(f1.w);
                H.u.x = (p0 & 0xffffu) | (p1 << 16);
                H.u.y = (p2 & 0xffffu) | (p3 << 16);
                H.u.z = (p4 & 0xffffu) | (p5 << 16);
                H.u.w = (p6 & 0xffffu) | (p7 << 16);
                L.u.x = (p0 >> 16) | (p1 & 0xffff0000u);
                L.u.y = (p2 >> 16) | (p3 & 0xffff0000u);
                L.u.z = (p4 >> 16) | (p5 & 0xffff0000u);
                L.u.w = (p6 >> 16) | (p7 & 0xffff0000u);
            } else {
                uint4 u0 = *(const uint4*)p0p;
                uint4 u1 = *(const uint4*)p1p;
                H.u.x = (u0.x & 0xffffu) | (u0.y << 16);
                H.u.y = (u0.z & 0xffffu) | (u0.w << 16);
                H.u.z = (u1.x & 0xffffu) | (u1.y << 16);
                H.u.w = (u1.z & 0xffffu) | (u1.w << 16);
                L.u.x = (u0.x >> 16) | (u0.y & 0xffff0000u);
                L.u.y = (u0.z >> 16) | (u0.w & 0xffff0000u);
                L.u.z = (u1.x >> 16) | (u1.y & 0xffff0000u);
                L.u.w = (u1.z >> 16) | (u1.w & 0xffff0000u);
            }
            fAh[i] = H.h;
            fAl[i] = L.h;
        }

#pragma unroll
        for (int j = 0; j < 4; ++j) {
            const int r = wn * 64 + j * 16 + lm;
            const int x = r & 7;
            uint4 u0 = *(const uint4*)&bufB[b][r * 32 + (((2 * q) ^ x) << 2)];
            uint4 u1 = *(const uint4*)&bufB[b][r * 32 + ((((2 * q) | 1) ^ x) << 2)];
            HL H, L;
            H.u.x = (u0.x & 0xffffu) | (u0.y << 16);
            H.u.y = (u0.z & 0xffffu) | (u0.w << 16);
            H.u.z = (u1.x & 0xffffu) | (u1.y << 16);
            H.u.w = (u1.z & 0xffffu) | (u1.w << 16);
            L.u.x = (u0.x >> 16) | (u0.y & 0xffff0000u);
            L.u.y = (u0.z >> 16) | (u0.w & 0xffff0000u);
            L.u.z = (u1.x >> 16) | (u1.y & 0xffff0000u);
            L.u.w = (u1.z >> 16) | (u1.w & 0xffff0000u);
            fBh[j] = H.h;
            fBl[j] = L.h;
        }

        __builtin_amdgcn_s_setprio(1);
#pragma unroll
        for (int i = 0; i < 4; ++i)
#pragma unroll
            for (int j = 0; j < 4; ++j)
                aH[i][j] = __builtin_amdgcn_mfma_f32_16x16x32_f16(fAh[i], fBh[j], aH[i][j], 0, 0, 0);
#pragma unroll
        for (int i = 0; i < 4; ++i)
#pragma unroll
            for (int j = 0; j < 4; ++j)
                aM[i][j] = __builtin_amdgcn_mfma_f32_16x16x32_f16(fAh[i], fBl[j], aM[i][j], 0, 0, 0);
#pragma unroll
        for (int i = 0; i < 4; ++i)
#pragma unroll
            for (int j = 0; j < 4; ++j)
                aM[i][j] = __builtin_amdgcn_mfma_f32_16x16x32_f16(fAl[i], fBh[j], aM[i][j], 0, 0, 0);
        __builtin_amdgcn_s_setprio(0);

        if (kt + 1 < NK) __syncthreads();
    }

    const float cM = 1.0f / 2048.0f;
#pragma unroll
    for (int i = 0; i < 4; ++i)
#pragma unroll
        for (int j = 0; j < 4; ++j)
            aH[i][j] = aH[i][j] + aM[i][j] * cM;

#pragma unroll
    for (int i = 0; i < 4; ++i)
#pragma unroll
        for (int r = 0; r < 4; ++r) {
            const int m = mBase + wm * 64 + i * 16 + q * 4 + r;
            if (m < M) {
#pragma unroll
                for (int j = 0; j < 4; ++j) {
                    const int c = nBase + wn * 64 + j * 16 + lm;
                    float v = fmaxf(aH[i][j][r], 0.f);
                    outS[(size_t)m * No + c] = splitf(v);
                }
            }
        }
}

// ---------------------------------------------------------------------------
// FUSED GEMM2+GEMM3 (R7): one block owns 128 rows end-to-end.
// Phase 1 (== R5 GEMM2): m = h @ W_lin2^T via DMA-staged K=256 loop,
//   row-L2-normalize in registers (sqv cross-wave exchange).
// Bridge: write normalized m as packed split-fp16 dwords into LDS, ALIASING
//   the dead staging buffers (64KB exactly). Chunk-XOR swizzle (chunk ^
//   (row&15)) on both write and read sides (plain ds ops -> any involution).
// Phase 2 (== GEMM3): p = W3 . m_norm, K=128 fully unrolled from LDS;
//   W3 fragments read DIRECT from global (64KB, L2-hot, no barriers so the
//   compiler hoists loads). Epilogue: +bias on cols 0-63, store p as split
//   fp16 tables pH (hi) + pL (lo) — replaces fp32 p at identical workspace
//   footprint; edge_k's fallback reconstructs hi + lo/2048 (~2^-21 rel).
// Eliminates the 102.4 MB mpl round-trip and one launch.
// ---------------------------------------------------------------------------
__global__ __launch_bounds__(256, 2)
void gemm23(const unsigned* __restrict__ Apl, const unsigned* __restrict__ W2i,
            const unsigned* __restrict__ W3i, const float* __restrict__ bias,
            unsigned short* __restrict__ pHo, unsigned short* __restrict__ pLo,
            int M)
{
    __shared__ __align__(16) unsigned smem[16384];   // 64KB: staging / m_lds
    __shared__ float sqv[128][2];
    unsigned (*bufA)[128 * 32] = (unsigned(*)[128 * 32])(smem);
    unsigned (*bufB)[128 * 32] = (unsigned(*)[128 * 32])(smem + 8192);
    unsigned* mld = smem;

    const int t     = threadIdx.x;
    const int w     = t >> 6;
    const int wm    = w >> 1;
    const int wn    = w & 1;
    const int lane  = t & 63;
    const int lm    = lane & 15;
    const int q     = lane >> 4;
    const int mBase = blockIdx.x * 128;

    const int col16 = (lane & 7) ^ (lane >> 3);
    const float cM = 1.0f / 2048.0f;

    f32x4 aH[4][4], aM[4][4];
#pragma unroll
    for (int i = 0; i < 4; ++i)
#pragma unroll
        for (int j = 0; j < 4; ++j) {
            aH[i][j] = (f32x4){0.f, 0.f, 0.f, 0.f};
            aM[i][j] = (f32x4){0.f, 0.f, 0.f, 0.f};
        }

    auto stage = [&](int sb, int kt) {
#pragma unroll
        for (int c = 0; c < 4; ++c) {
            const int row = w * 32 + c * 8 + (lane >> 3);
            unsigned* ldsA = &bufA[sb][w * 1024 + c * 256];
            unsigned* ldsB = &bufB[sb][w * 1024 + c * 256];
            int rgA = mBase + row; rgA = rgA < M ? rgA : M - 1;
            const unsigned* gA = Apl + (size_t)rgA * 256 + kt * 32 + col16 * 4;
            dma16(gA, ldsA);
            const unsigned* gB = W2i + (size_t)row * 256 + kt * 32 + col16 * 4;
            dma16(gB, ldsB);
        }
    };

    union HL { uint4 u; half8 h; };

    auto deint = [&](uint4 u0, uint4 u1, half8& hh, half8& hl) {
        HL H, L;
        H.u.x = (u0.x & 0xffffu) | (u0.y << 16);
        H.u.y = (u0.z & 0xffffu) | (u0.w << 16);
        H.u.z = (u1.x & 0xffffu) | (u1.y << 16);
        H.u.w = (u1.z & 0xffffu) | (u1.w << 16);
        L.u.x = (u0.x >> 16) | (u0.y & 0xffff0000u);
        L.u.y = (u0.z >> 16) | (u0.w & 0xffff0000u);
        L.u.z = (u1.x >> 16) | (u1.y & 0xffff0000u);
        L.u.w = (u1.z >> 16) | (u1.w & 0xffff0000u);
        hh = H.h; hl = L.h;
    };

    // ---------------- Phase 1: m = h @ W2^T (K=256) ----------------
    stage(0, 0);
    __syncthreads();

#pragma unroll 2
    for (int kt = 0; kt < 8; ++kt) {
        const int b = kt & 1;
        if (kt + 1 < 8) stage(b ^ 1, kt + 1);

        half8 fAh[4], fAl[4], fBh[4], fBl[4];
#pragma unroll
        for (int i = 0; i < 4; ++i) {
            const int r = wm * 64 + i * 16 + lm;
            const int x = r & 7;
            uint4 u0 = *(const uint4*)&bufA[b][r * 32 + (((2 * q) ^ x) << 2)];
            uint4 u1 = *(const uint4*)&bufA[b][r * 32 + ((((2 * q) | 1) ^ x) << 2)];
            deint(u0, u1, fAh[i], fAl[i]);
        }
#pragma unroll
        for (int j = 0; j < 4; ++j) {
            const int r = wn * 64 + j * 16 + lm;
            const int x = r & 7;
            uint4 u0 = *(const uint4*)&bufB[b][r * 32 + (((2 * q) ^ x) << 2)];
            uint4 u1 = *(const uint4*)&bufB[b][r * 32 + ((((2 * q) | 1) ^ x) << 2)];
            deint(u0, u1, fBh[j], fBl[j]);
        }

        __builtin_amdgcn_s_setprio(1);
#pragma unroll
        for (int i = 0; i < 4; ++i)
#pragma unroll
            for (int j = 0; j < 4; ++j)
                aH[i][j] = __builtin_amdgcn_mfma_f32_16x16x32_f16(fAh[i], fBh[j], aH[i][j], 0, 0, 0);
#pragma unroll
        for (int i = 0; i < 4; ++i)
#pragma unroll
            for (int j = 0; j < 4; ++j)
                aM[i][j] = __builtin_amdgcn_mfma_f32_16x16x32_f16(fAh[i], fBl[j], aM[i][j], 0, 0, 0);
#pragma unroll
        for (int i = 0; i < 4; ++i)
#pragma unroll
            for (int j = 0; j < 4; ++j)
                aM[i][j] = __builtin_amdgcn_mfma_f32_16x16x32_f16(fAl[i], fBh[j], aM[i][j], 0, 0, 0);
        __builtin_amdgcn_s_setprio(0);

        if (kt + 1 < 8) __syncthreads();
    }

#pragma unroll
    for (int i = 0; i < 4; ++i)
#pragma unroll
        for (int j = 0; j < 4; ++j)
            aH[i][j] = aH[i][j] + aM[i][j] * cM;

    // Row sum-of-squares -> sqv exchange (R2/R5-verified EPI=1 machinery).
#pragma unroll
    for (int i = 0; i < 4; ++i)
#pragma unroll
        for (int r = 0; r < 4; ++r) {
            float s = 0.f;
#pragma unroll
            for (int j = 0; j < 4; ++j) { float x = aH[i][j][r]; s = fmaf(x, x, s); }
#pragma unroll
            for (int off = 1; off < 16; off <<= 1) s += __shfl_xor(s, off, 16);
            if (lm == 0) sqv[wm * 64 + i * 16 + q * 4 + r][wn] = s;
        }
    __syncthreads();   // sqv ready; also: all staging-buf reads done (alias ok)

    // Normalize and write m to LDS (packed split dword, chunk-XOR swizzle).
#pragma unroll
    for (int i = 0; i < 4; ++i)
#pragma unroll
        for (int r = 0; r < 4; ++r) {
            const int rl = wm * 64 + i * 16 + q * 4 + r;
            const float nm = fmaxf(sqrtf(sqv[rl][0] + sqv[rl][1]), 1e-12f);
#pragma unroll
            for (int j = 0; j < 4; ++j) {
                const int col = wn * 64 + j * 16 + lm;
                const int ch  = (col >> 2) ^ (rl & 15);
                mld[rl * 128 + (ch << 2) + (col & 3)] = splitf(aH[i][j][r] / nm);
            }
        }
    __syncthreads();

    // ---------------- Phase 2: p = W3 . m_norm (K=128, from LDS) ----------
#pragma unroll
    for (int i = 0; i < 4; ++i)
#pragma unroll
        for (int j = 0; j < 4; ++j) {
            aH[i][j] = (f32x4){0.f, 0.f, 0.f, 0.f};
            aM[i][j] = (f32x4){0.f, 0.f, 0.f, 0.f};
        }

#pragma unroll
    for (int kt = 0; kt < 4; ++kt) {
        half8 fAh[4], fAl[4], fBh[4], fBl[4];
#pragma unroll
        for (int i = 0; i < 4; ++i) {
            const int row = wm * 64 + i * 16 + lm;
            const int x = row & 15;
            const int c0 = kt * 8 + 2 * q;
            uint4 u0 = *(const uint4*)&mld[row * 128 + ((c0 ^ x) << 2)];
            uint4 u1 = *(const uint4*)&mld[row * 128 + (((c0 + 1) ^ x) << 2)];
            deint(u0, u1, fAh[i], fAl[i]);
        }
#pragma unroll
        for (int j = 0; j < 4; ++j) {
            const int row = wn * 64 + j * 16 + lm;
            const unsigned* bp = W3i + (size_t)row * 128 + kt * 32 + q * 8;
            uint4 u0 = *(const uint4*)bp;
            uint4 u1 = *(const uint4*)(bp + 4);
            deint(u0, u1, fBh[j], fBl[j]);
        }

        __builtin_amdgcn_s_setprio(1);
#pragma unroll
        for (int i = 0; i < 4; ++i)
#pragma unroll
            for (int j = 0; j < 4; ++j)
                aH[i][j] = __builtin_amdgcn_mfma_f32_16x16x32_f16(fAh[i], fBh[j], aH[i][j], 0, 0, 0);
#pragma unroll
        for (int i = 0; i < 4; ++i)
#pragma unroll
            for (int j = 0; j < 4; ++j)
                aM[i][j] = __builtin_amdgcn_mfma_f32_16x16x32_f16(fAh[i], fBl[j], aM[i][j], 0, 0, 0);
#pragma unroll
        for (int i = 0; i < 4; ++i)
#pragma unroll
            for (int j = 0; j < 4; ++j)
                aM[i][j] = __builtin_amdgcn_mfma_f32_16x16x32_f16(fAl[i], fBh[j], aM[i][j], 0, 0, 0);
        __builtin_amdgcn_s_setprio(0);
    }

#pragma unroll
    for (int i = 0; i < 4; ++i)
#pragma unroll
        for (int j = 0; j < 4; ++j)
            aH[i][j] = aH[i][j] + aM[i][j] * cM;

    float bj[4] = {0.f, 0.f, 0.f, 0.f};
    if (wn == 0) {
#pragma unroll
        for (int j = 0; j < 4; ++j) bj[j] = bias[j * 16 + lm];
    }

#pragma unroll
    for (int i = 0; i < 4; ++i)
#pragma unroll
        for (int r = 0; r < 4; ++r) {
            const int m = mBase + wm * 64 + i * 16 + q * 4 + r;
            if (m < M) {
#pragma unroll
                for (int j = 0; j < 4; ++j) {
                    const int c = wn * 64 + j * 16 + lm;
                    const float v = aH[i][j][r] + bj[j];
                    const unsigned pk = splitf(v);
                    pHo[(size_t)m * 128 + c] = (unsigned short)(pk & 0xffffu);
                    pLo[(size_t)m * 128 + c] = (unsigned short)(pk >> 16);
                }
            }
        }
}

// ---------------------------------------------------------------------------
// Edge kernel: 128 edges/block, 16 lanes/edge, 8 edges/lane-group.
// Fast path gathers the fp16-hi p-table (8 B/lane per edge-half); decision
// needs only the SIGN of gap = sum relu(a+c)*(w0-w1) + dB + dg. Certified
// bound: |fast gap - arbiter gap| <= 2^-10 * sum |dk|*(|a|+|c|) + 2e-5; if
// |gap| <= bound, gather the lo-plane and recompute with hi + lo/2048
// (~2^-21 rel — the arbiter). Butterfly results bit-identical across lanes
// -> branch uniform per 16-lane group.
// ---------------------------------------------------------------------------
#define EPB 128
__global__ __launch_bounds__(256, 4)
void edge_k(const unsigned short* __restrict__ pH, const unsigned short* __restrict__ pL,
            const int* __restrict__ ei, const float* __restrict__ gum,
            const float* __restrict__ W2, const float* __restrict__ b2,
            float* __restrict__ out)
{
    __shared__ int   sidx[EPB];
    __shared__ int   didx[EPB];
    __shared__ float gl[2 * EPB];
    __shared__ float act[EPB];

    const int t  = threadIdx.x;
    const int e0 = blockIdx.x * EPB;

    if (t < EPB) sidx[t] = ei[e0 + t];
    else         didx[t - EPB] = ei[EROW + e0 + (t - EPB)];
    gl[t] = gum[(size_t)e0 * 2 + t];
    __syncthreads();

    const int j   = t & 15;
    const int grp = t >> 4;
    const float4 w0 = ld4(&W2[j * 4]);
    const float4 w1 = ld4(&W2[64 + j * 4]);
    const float4 dk = make_float4(w0.x - w1.x, w0.y - w1.y,
                                  w0.z - w1.z, w0.w - w1.w);
    const float4 dw = make_float4(fabsf(dk.x), fabsf(dk.y),
                                  fabsf(dk.z), fabsf(dk.w));
    const float b20 = b2[0], b21 = b2[1];
    const float dB  = b20 - b21;

    union U8 { uint2 u; half4 h; };
    U8 ua[8], ub[8];
#pragma unroll
    for (int it = 0; it < 8; ++it) {
        const int el = grp * 8 + it;
        ua[it].u = *(const uint2*)&pH[(size_t)sidx[el] * 128 + j * 4];
        ub[it].u = *(const uint2*)&pH[(size_t)didx[el] * 128 + 64 + j * 4];
    }

#pragma unroll
    for (int it = 0; it < 8; ++it) {
        const int el = grp * 8 + it;
        const float a0 = (float)ua[it].h[0], a1 = (float)ua[it].h[1];
        const float a2 = (float)ua[it].h[2], a3 = (float)ua[it].h[3];
        const float c0 = (float)ub[it].h[0], c1 = (float)ub[it].h[1];
        const float c2 = (float)ub[it].h[2], c3 = (float)ub[it].h[3];
        const float r0 = fmaxf(a0 + c0, 0.f);
        const float r1 = fmaxf(a1 + c1, 0.f);
        const float r2 = fmaxf(a2 + c2, 0.f);
        const float r3 = fmaxf(a3 + c3, 0.f);
        float sc = r0 * dk.x + r1 * dk.y + r2 * dk.z + r3 * dk.w;
        float eb = dw.x * (fabsf(a0) + fabsf(c0)) + dw.y * (fabsf(a1) + fabsf(c1))
                 + dw.z * (fabsf(a2) + fabsf(c2)) + dw.w * (fabsf(a3) + fabsf(c3));
#pragma unroll
        for (int off = 1; off < 16; off <<= 1) {
            sc += __shfl_xor(sc, off, 16);
            eb += __shfl_xor(eb, off, 16);
        }
        const float g0 = gl[el * 2], g1 = gl[el * 2 + 1];
        const float gap = sc + dB + (g0 - g1);
        const float bound = eb * 0.0009765625f + 2e-5f;   // 2^-10 * eb + slack
        float av;
        if (fabsf(gap) > bound) {
            av = (gap >= 0.f) ? 1.f : 0.f;
        } else {
            // Arbiter: reconstruct hi + lo/2048 (rare; uniform per 16-lane grp).
            U8 la, lb;
            la.u = *(const uint2*)&pL[(size_t)sidx[el] * 128 + j * 4];
            lb.u = *(const uint2*)&pL[(size_t)didx[el] * 128 + 64 + j * 4];
            const float iS = 1.0f / 2048.0f;
            const float q0 = fmaxf((a0 + (float)la.h[0] * iS) + (c0 + (float)lb.h[0] * iS), 0.f);
            const float q1 = fmaxf((a1 + (float)la.h[1] * iS) + (c1 + (float)lb.h[1] * iS), 0.f);
            const float q2 = fmaxf((a2 + (float)la.h[2] * iS) + (c2 + (float)lb.h[2] * iS), 0.f);
            const float q3 = fmaxf((a3 + (float)la.h[3] * iS) + (c3 + (float)lb.h[3] * iS), 0.f);
            float t0 = q0 * w0.x + q1 * w0.y + q2 * w0.z + q3 * w0.w;
            float t1 = q0 * w1.x + q1 * w1.y + q2 * w1.z + q3 * w1.w;
#pragma unroll
            for (int off = 1; off < 16; off <<= 1) {
                t0 += __shfl_xor(t0, off, 16);
                t1 += __shfl_xor(t1, off, 16);
            }
            const float ge = (t0 + b20 + g0) - (t1 + b21 + g1);
            av = (ge >= 0.f) ? 1.f : 0.f;
        }
        if (j == 0) act[el] = av;
    }
    __syncthreads();

    if (t < EPB) {
        const float a = act[t];
        const size_t e = (size_t)e0 + t;
        out[e]                  = a;
        out[EE + e]             = 1.f - a;
        out[2 * (size_t)EE + e] = 1.f - a;
    }
}

// ---------------------------------------------------------------------------
extern "C" void kernel_launch(void* const* d_in, const int* in_sizes, int n_in,
                              void* d_out, int out_size, void* d_ws, size_t ws_size,
                              hipStream_t stream)
{
    const float* trace  = (const float*)d_in[0];   // (2,100000,128)
    const float* W_lin  = (const float*)d_in[1];   // (256,256)
    const float* W_lin2 = (const float*)d_in[2];   // (128,256)
    const float* W_fc1  = (const float*)d_in[3];   // (64,256)
    const float* b_fc1  = (const float*)d_in[4];   // (64,)
    const float* W_fc2  = (const float*)d_in[5];   // (2,64)
    const float* b_fc2  = (const float*)d_in[6];   // (2,)
    const float* gum    = (const float*)d_in[7];   // (1600000,2)
    const int*   ei     = (const int*)  d_in[8];   // (2,4800000)
    float*       out    = (float*)d_out;           // (4800000,)

    // Workspace (154 MB, SAME footprint as before):
    // [hpl 102.4MB][pH 25.6MB][pL 25.6MB][weight planes 0.46MB].
    // gemm23 reads hpl + weights, writes pH/pL — all regions disjoint.
    char* ws = (char*)d_ws;
    unsigned*       hpl = (unsigned*)ws;
    unsigned short* pH  = (unsigned short*)(ws + (size_t)NN * 256 * 4);
    unsigned short* pL  = (unsigned short*)(ws + (size_t)NN * 256 * 4 + (size_t)NN * 128 * 2);
    unsigned*       W1i = (unsigned*)(ws + (size_t)NN * 256 * 4 + (size_t)NN * 128 * 4);
    unsigned*       W2i = W1i + 65536;
    unsigned*       W3i = W2i + 32768;

    // Split weights into fp16 hi/lo interleaved planes.
    prep_w<<<448, 256, 0, stream>>>(W_lin, W_lin2, W_fc1, W1i, W2i, W3i);

    const int mB = (NN + 127) / 128;   // 782

    // h = relu(x @ W_lin^T), stored split (R5-verified kernel)
    gemm_mfma<0, 256><<<dim3(mB, 2), 256, 0, stream>>>(trace, W1i, hpl, NN, 256);
    // fused: m = normalize(h @ W_lin2^T); p = W3 . m (+bias), split pH/pL
    gemm23<<<mB, 256, 0, stream>>>(hpl, W2i, W3i, b_fc1, pH, pL, NN);
    // per-edge score + hard mask (fp16 fast path, certified split fallback)
    edge_k<<<EE / EPB, 256, 0, stream>>>(pH, pL, ei, gum, W_fc2, b_fc2, out);
}

// Round 11
// 352.132 us; speedup vs baseline: 1.1097x; 1.0361x over previous
//
#include <hip/hip_runtime.h>

// Problem constants (fixed by the reference's setup_inputs)
#define NN   100000      // nodes
#define EE   1600000     // num_edge
#define EROW 4800000     // edge_index row length (3*NUM_EDGE)

typedef _Float16 half8 __attribute__((ext_vector_type(8)));
typedef _Float16 half4 __attribute__((ext_vector_type(4)));
typedef float    f32x4 __attribute__((ext_vector_type(4)));

__device__ __forceinline__ float4 ld4(const float* p){ return *(const float4*)p; }

// Split fp32 -> (hi fp16) + (lo fp16, scaled by 2048). Packed lo16=hi, hi16=lo.
__device__ __forceinline__ unsigned splitf(float v) {
    _Float16 h = (_Float16)v;
    float r = v - (float)h;
    _Float16 l = (_Float16)(r * 2048.0f);
    union { _Float16 f; unsigned short u; } uh, ul;
    uh.f = h; ul.f = l;
    return (unsigned)uh.u | ((unsigned)ul.u << 16);
}

// Async global->LDS DMA, 16 B per lane. LDS dest = wave-uniform base + lane*16.
__device__ __forceinline__ void dma16(const void* g, void* l) {
    __builtin_amdgcn_global_load_lds(
        (const __attribute__((address_space(1))) unsigned*)((size_t)g),
        (__attribute__((address_space(3))) unsigned*)((size_t)l),
        16, 0, 0);
}

// ---------------------------------------------------------------------------
// Weight prep: split W_lin (256x256), W_lin2 (128x256), repacked W_fc1
// (128x128: row j = W_fc1[j&63][(j>>6)*128 ..]) into interleaved half2 planes.
// ---------------------------------------------------------------------------
__global__ __launch_bounds__(256)
void prep_w(const float* __restrict__ W1, const float* __restrict__ W2,
            const float* __restrict__ W3, unsigned* __restrict__ o1,
            unsigned* __restrict__ o2, unsigned* __restrict__ o3)
{
    int idx = blockIdx.x * 256 + threadIdx.x;   // 448 blocks = 114688 threads
    if (idx < 65536) {
        o1[idx] = splitf(W1[idx]);
    } else if (idx < 98304) {
        int i = idx - 65536;
        o2[i] = splitf(W2[i]);
    } else {
        int i = idx - 98304;
        int j = i >> 7, k = i & 127;
        o3[i] = splitf(W3[(j & 63) * 256 + (j >> 6) * 128 + k]);
    }
}

// ---------------------------------------------------------------------------
// GEMM1 (R5-verified structure): C[M x No] = A[M x K] @ B[No x K]^T, relu,
// split-store. 256 thr = 4 waves 2x2, wave tile 64x64. DMA staging of raw
// tiles, double-buffered, ONE __syncthreads per K-step. LDS XOR involution:
// chunk c of row r holds global chunk c^(r&7); DMA pre-swizzles the global
// source with col16 = (l&7)^(l>>3); reads XOR the chunk index with (r&7).
// SRCA 0: A = trace fp32 (2-plane, split on read). 1: interleaved plane.
// ---------------------------------------------------------------------------
template<int SRCA, int K>
__global__ __launch_bounds__(256, 2)
void gemm_mfma(const void* __restrict__ Asrc, const unsigned* __restrict__ Bw,
               unsigned* __restrict__ outS, int M, int No)
{
    __shared__ __align__(16) unsigned bufA[2][128 * 32];
    __shared__ __align__(16) unsigned bufB[2][128 * 32];

    const int t     = threadIdx.x;
    const int w     = t >> 6;
    const int wm    = w >> 1;
    const int wn    = w & 1;
    const int lane  = t & 63;
    const int lm    = lane & 15;
    const int q     = lane >> 4;
    const int mBase = blockIdx.x * 128;
    const int nBase = blockIdx.y * 128;

    const int col16 = (lane & 7) ^ (lane >> 3);

    f32x4 aH[4][4], aM[4][4];
#pragma unroll
    for (int i = 0; i < 4; ++i)
#pragma unroll
        for (int j = 0; j < 4; ++j) {
            aH[i][j] = (f32x4){0.f, 0.f, 0.f, 0.f};
            aM[i][j] = (f32x4){0.f, 0.f, 0.f, 0.f};
        }

    auto stage = [&](int sb, int kt) {
#pragma unroll
        for (int c = 0; c < 4; ++c) {
            const int row = w * 32 + c * 8 + (lane >> 3);
            unsigned* ldsA = &bufA[sb][w * 1024 + c * 256];
            unsigned* ldsB = &bufB[sb][w * 1024 + c * 256];
            int rgA = mBase + row; rgA = rgA < M ? rgA : M - 1;
            if (SRCA == 0) {
                const int kg = kt * 32;
                const float* gA = (const float*)Asrc
                    + (size_t)(kg >> 7) * ((size_t)NN * 128)
                    + (size_t)rgA * 128 + (kg & 127) + col16 * 4;
                dma16(gA, ldsA);
            } else {
                const unsigned* gA = (const unsigned*)Asrc
                    + (size_t)rgA * K + kt * 32 + col16 * 4;
                dma16(gA, ldsA);
            }
            const unsigned* gB = Bw + (size_t)(nBase + row) * K + kt * 32 + col16 * 4;
            dma16(gB, ldsB);
        }
    };

    union HL { uint4 u; half8 h; };

    constexpr int NK = K / 32;
    stage(0, 0);
    __syncthreads();

#pragma unroll 2
    for (int kt = 0; kt < NK; ++kt) {
        const int b = kt & 1;
        if (kt + 1 < NK) stage(b ^ 1, kt + 1);

        half8 fAh[4], fAl[4], fBh[4], fBl[4];

#pragma unroll
        for (int i = 0; i < 4; ++i) {
            const int r = wm * 64 + i * 16 + lm;
            const int x = r & 7;
            const unsigned* p0p = &bufA[b][r * 32 + (((2 * q) ^ x) << 2)];
            const unsigned* p1p = &bufA[b][r * 32 + ((((2 * q) | 1) ^ x) << 2)];
            HL H, L;
            if (SRCA == 0) {
                float4 f0 = *(const float4*)p0p;
                float4 f1 = *(const float4*)p1p;
                unsigned p0 = splitf(f0.x), p1 = splitf(f0.y);
                unsigned p2 = splitf(f0.z), p3 = splitf(f0.w);
                unsigned p4 = splitf(f1.x), p5 = splitf(f1.y);
                unsigned p6 = splitf(f1.z), p7 = splitf(f1.w);
                H.u.x = (p0 & 0xffffu) | (p1 << 16);
                H.u.y = (p2 & 0xffffu) | (p3 << 16);
                H.u.z = (p4 & 0xffffu) | (p5 << 16);
                H.u.w = (p6 & 0xffffu) | (p7 << 16);
                L.u.x = (p0 >> 16) | (p1 & 0xffff0000u);
                L.u.y = (p2 >> 16) | (p3 & 0xffff0000u);
                L.u.z = (p4 >> 16) | (p5 & 0xffff0000u);
                L.u.w = (p6 >> 16) | (p7 & 0xffff0000u);
            } else {
                uint4 u0 = *(const uint4*)p0p;
                uint4 u1 = *(const uint4*)p1p;
                H.u.x = (u0.x & 0xffffu) | (u0.y << 16);
                H.u.y = (u0.z & 0xffffu) | (u0.w << 16);
                H.u.z = (u1.x & 0xffffu) | (u1.y << 16);
                H.u.w = (u1.z & 0xffffu) | (u1.w << 16);
                L.u.x = (u0.x >> 16) | (u0.y & 0xffff0000u);
                L.u.y = (u0.z >> 16) | (u0.w & 0xffff0000u);
                L.u.z = (u1.x >> 16) | (u1.y & 0xffff0000u);
                L.u.w = (u1.z >> 16) | (u1.w & 0xffff0000u);
            }
            fAh[i] = H.h;
            fAl[i] = L.h;
        }

#pragma unroll
        for (int j = 0; j < 4; ++j) {
            const int r = wn * 64 + j * 16 + lm;
            const int x = r & 7;
            uint4 u0 = *(const uint4*)&bufB[b][r * 32 + (((2 * q) ^ x) << 2)];
            uint4 u1 = *(const uint4*)&bufB[b][r * 32 + ((((2 * q) | 1) ^ x) << 2)];
            HL H, L;
            H.u.x = (u0.x & 0xffffu) | (u0.y << 16);
            H.u.y = (u0.z & 0xffffu) | (u0.w << 16);
            H.u.z = (u1.x & 0xffffu) | (u1.y << 16);
            H.u.w = (u1.z & 0xffffu) | (u1.w << 16);
            L.u.x = (u0.x >> 16) | (u0.y & 0xffff0000u);
            L.u.y = (u0.z >> 16) | (u0.w & 0xffff0000u);
            L.u.z = (u1.x >> 16) | (u1.y & 0xffff0000u);
            L.u.w = (u1.z >> 16) | (u1.w & 0xffff0000u);
            fBh[j] = H.h;
            fBl[j] = L.h;
        }

        __builtin_amdgcn_s_setprio(1);
#pragma unroll
        for (int i = 0; i < 4; ++i)
#pragma unroll
            for (int j = 0; j < 4; ++j)
                aH[i][j] = __builtin_amdgcn_mfma_f32_16x16x32_f16(fAh[i], fBh[j], aH[i][j], 0, 0, 0);
#pragma unroll
        for (int i = 0; i < 4; ++i)
#pragma unroll
            for (int j = 0; j < 4; ++j)
                aM[i][j] = __builtin_amdgcn_mfma_f32_16x16x32_f16(fAh[i], fBl[j], aM[i][j], 0, 0, 0);
#pragma unroll
        for (int i = 0; i < 4; ++i)
#pragma unroll
            for (int j = 0; j < 4; ++j)
                aM[i][j] = __builtin_amdgcn_mfma_f32_16x16x32_f16(fAl[i], fBh[j], aM[i][j], 0, 0, 0);
        __builtin_amdgcn_s_setprio(0);

        if (kt + 1 < NK) __syncthreads();
    }

    const float cM = 1.0f / 2048.0f;
#pragma unroll
    for (int i = 0; i < 4; ++i)
#pragma unroll
        for (int j = 0; j < 4; ++j)
            aH[i][j] = aH[i][j] + aM[i][j] * cM;

#pragma unroll
    for (int i = 0; i < 4; ++i)
#pragma unroll
        for (int r = 0; r < 4; ++r) {
            const int m = mBase + wm * 64 + i * 16 + q * 4 + r;
            if (m < M) {
#pragma unroll
                for (int j = 0; j < 4; ++j) {
                    const int c = nBase + wn * 64 + j * 16 + lm;
                    float v = fmaxf(aH[i][j][r], 0.f);
                    outS[(size_t)m * No + c] = splitf(v);
                }
            }
        }
}

// ---------------------------------------------------------------------------
// FUSED GEMM2+GEMM3 (R8-verified): one block owns 128 rows end-to-end.
// Phase 1 (== R5 GEMM2): m = h @ W_lin2^T via DMA-staged K=256 loop,
//   row-L2-normalize in registers (sqv cross-wave exchange).
// Bridge: write normalized m as packed split-fp16 dwords into LDS, ALIASING
//   the dead staging buffers (64KB exactly). Chunk-XOR swizzle (chunk ^
//   (row&15)) on both write and read sides (plain ds ops -> any involution).
// Phase 2 (== GEMM3): p = W3 . m_norm, K=128 fully unrolled from LDS;
//   W3 fragments read DIRECT from global (64KB, L2-hot, no barriers so the
//   compiler hoists loads). Epilogue: +bias on cols 0-63, store p as split
//   fp16 tables pH (hi) + pL (lo); edge_k's fallback reconstructs
//   hi + lo/2048 (~2^-21 rel).
// ---------------------------------------------------------------------------
__global__ __launch_bounds__(256, 2)
void gemm23(const unsigned* __restrict__ Apl, const unsigned* __restrict__ W2i,
            const unsigned* __restrict__ W3i, const float* __restrict__ bias,
            unsigned short* __restrict__ pHo, unsigned short* __restrict__ pLo,
            int M)
{
    __shared__ __align__(16) unsigned smem[16384];   // 64KB: staging / m_lds
    __shared__ float sqv[128][2];
    unsigned (*bufA)[128 * 32] = (unsigned(*)[128 * 32])(smem);
    unsigned (*bufB)[128 * 32] = (unsigned(*)[128 * 32])(smem + 8192);
    unsigned* mld = smem;

    const int t     = threadIdx.x;
    const int w     = t >> 6;
    const int wm    = w >> 1;
    const int wn    = w & 1;
    const int lane  = t & 63;
    const int lm    = lane & 15;
    const int q     = lane >> 4;
    const int mBase = blockIdx.x * 128;

    const int col16 = (lane & 7) ^ (lane >> 3);
    const float cM = 1.0f / 2048.0f;

    f32x4 aH[4][4], aM[4][4];
#pragma unroll
    for (int i = 0; i < 4; ++i)
#pragma unroll
        for (int j = 0; j < 4; ++j) {
            aH[i][j] = (f32x4){0.f, 0.f, 0.f, 0.f};
            aM[i][j] = (f32x4){0.f, 0.f, 0.f, 0.f};
        }

    auto stage = [&](int sb, int kt) {
#pragma unroll
        for (int c = 0; c < 4; ++c) {
            const int row = w * 32 + c * 8 + (lane >> 3);
            unsigned* ldsA = &bufA[sb][w * 1024 + c * 256];
            unsigned* ldsB = &bufB[sb][w * 1024 + c * 256];
            int rgA = mBase + row; rgA = rgA < M ? rgA : M - 1;
            const unsigned* gA = Apl + (size_t)rgA * 256 + kt * 32 + col16 * 4;
            dma16(gA, ldsA);
            const unsigned* gB = W2i + (size_t)row * 256 + kt * 32 + col16 * 4;
            dma16(gB, ldsB);
        }
    };

    union HL { uint4 u; half8 h; };

    auto deint = [&](uint4 u0, uint4 u1, half8& hh, half8& hl) {
        HL H, L;
        H.u.x = (u0.x & 0xffffu) | (u0.y << 16);
        H.u.y = (u0.z & 0xffffu) | (u0.w << 16);
        H.u.z = (u1.x & 0xffffu) | (u1.y << 16);
        H.u.w = (u1.z & 0xffffu) | (u1.w << 16);
        L.u.x = (u0.x >> 16) | (u0.y & 0xffff0000u);
        L.u.y = (u0.z >> 16) | (u0.w & 0xffff0000u);
        L.u.z = (u1.x >> 16) | (u1.y & 0xffff0000u);
        L.u.w = (u1.z >> 16) | (u1.w & 0xffff0000u);
        hh = H.h; hl = L.h;
    };

    // ---------------- Phase 1: m = h @ W2^T (K=256) ----------------
    stage(0, 0);
    __syncthreads();

#pragma unroll 2
    for (int kt = 0; kt < 8; ++kt) {
        const int b = kt & 1;
        if (kt + 1 < 8) stage(b ^ 1, kt + 1);

        half8 fAh[4], fAl[4], fBh[4], fBl[4];
#pragma unroll
        for (int i = 0; i < 4; ++i) {
            const int r = wm * 64 + i * 16 + lm;
            const int x = r & 7;
            uint4 u0 = *(const uint4*)&bufA[b][r * 32 + (((2 * q) ^ x) << 2)];
            uint4 u1 = *(const uint4*)&bufA[b][r * 32 + ((((2 * q) | 1) ^ x) << 2)];
            deint(u0, u1, fAh[i], fAl[i]);
        }
#pragma unroll
        for (int j = 0; j < 4; ++j) {
            const int r = wn * 64 + j * 16 + lm;
            const int x = r & 7;
            uint4 u0 = *(const uint4*)&bufB[b][r * 32 + (((2 * q) ^ x) << 2)];
            uint4 u1 = *(const uint4*)&bufB[b][r * 32 + ((((2 * q) | 1) ^ x) << 2)];
            deint(u0, u1, fBh[j], fBl[j]);
        }

        __builtin_amdgcn_s_setprio(1);
#pragma unroll
        for (int i = 0; i < 4; ++i)
#pragma unroll
            for (int j = 0; j < 4; ++j)
                aH[i][j] = __builtin_amdgcn_mfma_f32_16x16x32_f16(fAh[i], fBh[j], aH[i][j], 0, 0, 0);
#pragma unroll
        for (int i = 0; i < 4; ++i)
#pragma unroll
            for (int j = 0; j < 4; ++j)
                aM[i][j] = __builtin_amdgcn_mfma_f32_16x16x32_f16(fAh[i], fBl[j], aM[i][j], 0, 0, 0);
#pragma unroll
        for (int i = 0; i < 4; ++i)
#pragma unroll
            for (int j = 0; j < 4; ++j)
                aM[i][j] = __builtin_amdgcn_mfma_f32_16x16x32_f16(fAl[i], fBh[j], aM[i][j], 0, 0, 0);
        __builtin_amdgcn_s_setprio(0);

        if (kt + 1 < 8) __syncthreads();
    }

#pragma unroll
    for (int i = 0; i < 4; ++i)
#pragma unroll
        for (int j = 0; j < 4; ++j)
            aH[i][j] = aH[i][j] + aM[i][j] * cM;

    // Row sum-of-squares -> sqv exchange (R2/R5-verified EPI=1 machinery).
#pragma unroll
    for (int i = 0; i < 4; ++i)
#pragma unroll
        for (int r = 0; r < 4; ++r) {
            float s = 0.f;
#pragma unroll
            for (int j = 0; j < 4; ++j) { float x = aH[i][j][r]; s = fmaf(x, x, s); }
#pragma unroll
            for (int off = 1; off < 16; off <<= 1) s += __shfl_xor(s, off, 16);
            if (lm == 0) sqv[wm * 64 + i * 16 + q * 4 + r][wn] = s;
        }
    __syncthreads();   // sqv ready; also: all staging-buf reads done (alias ok)

    // Normalize and write m to LDS (packed split dword, chunk-XOR swizzle).
#pragma unroll
    for (int i = 0; i < 4; ++i)
#pragma unroll
        for (int r = 0; r < 4; ++r) {
            const int rl = wm * 64 + i * 16 + q * 4 + r;
            const float nm = fmaxf(sqrtf(sqv[rl][0] + sqv[rl][1]), 1e-12f);
#pragma unroll
            for (int j = 0; j < 4; ++j) {
                const int col = wn * 64 + j * 16 + lm;
                const int ch  = (col >> 2) ^ (rl & 15);
                mld[rl * 128 + (ch << 2) + (col & 3)] = splitf(aH[i][j][r] / nm);
            }
        }
    __syncthreads();

    // ---------------- Phase 2: p = W3 . m_norm (K=128, from LDS) ----------
#pragma unroll
    for (int i = 0; i < 4; ++i)
#pragma unroll
        for (int j = 0; j < 4; ++j) {
            aH[i][j] = (f32x4){0.f, 0.f, 0.f, 0.f};
            aM[i][j] = (f32x4){0.f, 0.f, 0.f, 0.f};
        }

#pragma unroll
    for (int kt = 0; kt < 4; ++kt) {
        half8 fAh[4], fAl[4], fBh[4], fBl[4];
#pragma unroll
        for (int i = 0; i < 4; ++i) {
            const int row = wm * 64 + i * 16 + lm;
            const int x = row & 15;
            const int c0 = kt * 8 + 2 * q;
            uint4 u0 = *(const uint4*)&mld[row * 128 + ((c0 ^ x) << 2)];
            uint4 u1 = *(const uint4*)&mld[row * 128 + (((c0 + 1) ^ x) << 2)];
            deint(u0, u1, fAh[i], fAl[i]);
        }
#pragma unroll
        for (int j = 0; j < 4; ++j) {
            const int row = wn * 64 + j * 16 + lm;
            const unsigned* bp = W3i + (size_t)row * 128 + kt * 32 + q * 8;
            uint4 u0 = *(const uint4*)bp;
            uint4 u1 = *(const uint4*)(bp + 4);
            deint(u0, u1, fBh[j], fBl[j]);
        }

        __builtin_amdgcn_s_setprio(1);
#pragma unroll
        for (int i = 0; i < 4; ++i)
#pragma unroll
            for (int j = 0; j < 4; ++j)
                aH[i][j] = __builtin_amdgcn_mfma_f32_16x16x32_f16(fAh[i], fBh[j], aH[i][j], 0, 0, 0);
#pragma unroll
        for (int i = 0; i < 4; ++i)
#pragma unroll
            for (int j = 0; j < 4; ++j)
                aM[i][j] = __builtin_amdgcn_mfma_f32_16x16x32_f16(fAh[i], fBl[j], aM[i][j], 0, 0, 0);
#pragma unroll
        for (int i = 0; i < 4; ++i)
#pragma unroll
            for (int j = 0; j < 4; ++j)
                aM[i][j] = __builtin_amdgcn_mfma_f32_16x16x32_f16(fAl[i], fBh[j], aM[i][j], 0, 0, 0);
        __builtin_amdgcn_s_setprio(0);
    }

#pragma unroll
    for (int i = 0; i < 4; ++i)
#pragma unroll
        for (int j = 0; j < 4; ++j)
            aH[i][j] = aH[i][j] + aM[i][j] * cM;

    float bj[4] = {0.f, 0.f, 0.f, 0.f};
    if (wn == 0) {
#pragma unroll
        for (int j = 0; j < 4; ++j) bj[j] = bias[j * 16 + lm];
    }

#pragma unroll
    for (int i = 0; i < 4; ++i)
#pragma unroll
        for (int r = 0; r < 4; ++r) {
            const int m = mBase + wm * 64 + i * 16 + q * 4 + r;
            if (m < M) {
#pragma unroll
                for (int j = 0; j < 4; ++j) {
                    const int c = wn * 64 + j * 16 + lm;
                    const float v = aH[i][j][r] + bj[j];
                    const unsigned pk = splitf(v);
                    pHo[(size_t)m * 128 + c] = (unsigned short)(pk & 0xffffu);
                    pLo[(size_t)m * 128 + c] = (unsigned short)(pk >> 16);
                }
            }
        }
}

// ---------------------------------------------------------------------------
// Edge kernel: 128 edges/block, 16 lanes/edge, 8 edges/lane-group.
// Fast path gathers the fp16-hi p-table (8 B/lane per edge-half); decision
// needs only the SIGN of gap = sum relu(a+c)*(w0-w1) + dB + dg. Certified
// bound: |fast gap - arbiter gap| <= 2^-10 * sum |dk|*(|a|+|c|) + 2e-5; if
// |gap| <= bound, gather the lo-plane and recompute with hi + lo/2048
// (~2^-21 rel — the arbiter). Butterfly results bit-identical across lanes
// -> branch uniform per 16-lane group.
// ---------------------------------------------------------------------------
#define EPB 128
__global__ __launch_bounds__(256, 4)
void edge_k(const unsigned short* __restrict__ pH, const unsigned short* __restrict__ pL,
            const int* __restrict__ ei, const float* __restrict__ gum,
            const float* __restrict__ W2, const float* __restrict__ b2,
            float* __restrict__ out)
{
    __shared__ int   sidx[EPB];
    __shared__ int   didx[EPB];
    __shared__ float gl[2 * EPB];
    __shared__ float act[EPB];

    const int t  = threadIdx.x;
    const int e0 = blockIdx.x * EPB;

    if (t < EPB) sidx[t] = ei[e0 + t];
    else         didx[t - EPB] = ei[EROW + e0 + (t - EPB)];
    gl[t] = gum[(size_t)e0 * 2 + t];
    __syncthreads();

    const int j   = t & 15;
    const int grp = t >> 4;
    const float4 w0 = ld4(&W2[j * 4]);
    const float4 w1 = ld4(&W2[64 + j * 4]);
    const float4 dk = make_float4(w0.x - w1.x, w0.y - w1.y,
                                  w0.z - w1.z, w0.w - w1.w);
    const float4 dw = make_float4(fabsf(dk.x), fabsf(dk.y),
                                  fabsf(dk.z), fabsf(dk.w));
    const float b20 = b2[0], b21 = b2[1];
    const float dB  = b20 - b21;

    union U8 { uint2 u; half4 h; };
    U8 ua[8], ub[8];
#pragma unroll
    for (int it = 0; it < 8; ++it) {
        const int el = grp * 8 + it;
        ua[it].u = *(const uint2*)&pH[(size_t)sidx[el] * 128 + j * 4];
        ub[it].u = *(const uint2*)&pH[(size_t)didx[el] * 128 + 64 + j * 4];
    }

#pragma unroll
    for (int it = 0; it < 8; ++it) {
        const int el = grp * 8 + it;
        const float a0 = (float)ua[it].h[0], a1 = (float)ua[it].h[1];
        const float a2 = (float)ua[it].h[2], a3 = (float)ua[it].h[3];
        const float c0 = (float)ub[it].h[0], c1 = (float)ub[it].h[1];
        const float c2 = (float)ub[it].h[2], c3 = (float)ub[it].h[3];
        const float r0 = fmaxf(a0 + c0, 0.f);
        const float r1 = fmaxf(a1 + c1, 0.f);
        const float r2 = fmaxf(a2 + c2, 0.f);
        const float r3 = fmaxf(a3 + c3, 0.f);
        float sc = r0 * dk.x + r1 * dk.y + r2 * dk.z + r3 * dk.w;
        float eb = dw.x * (fabsf(a0) + fabsf(c0)) + dw.y * (fabsf(a1) + fabsf(c1))
                 + dw.z * (fabsf(a2) + fabsf(c2)) + dw.w * (fabsf(a3) + fabsf(c3));
#pragma unroll
        for (int off = 1; off < 16; off <<= 1) {
            sc += __shfl_xor(sc, off, 16);
            eb += __shfl_xor(eb, off, 16);
        }
        const float g0 = gl[el * 2], g1 = gl[el * 2 + 1];
        const float gap = sc + dB + (g0 - g1);
        const float bound = eb * 0.0009765625f + 2e-5f;   // 2^-10 * eb + slack
        float av;
        if (fabsf(gap) > bound) {
            av = (gap >= 0.f) ? 1.f : 0.f;
        } else {
            // Arbiter: reconstruct hi + lo/2048 (rare; uniform per 16-lane grp).
            U8 la, lb;
            la.u = *(const uint2*)&pL[(size_t)sidx[el] * 128 + j * 4];
            lb.u = *(const uint2*)&pL[(size_t)didx[el] * 128 + 64 + j * 4];
            const float iS = 1.0f / 2048.0f;
            const float q0 = fmaxf((a0 + (float)la.h[0] * iS) + (c0 + (float)lb.h[0] * iS), 0.f);
            const float q1 = fmaxf((a1 + (float)la.h[1] * iS) + (c1 + (float)lb.h[1] * iS), 0.f);
            const float q2 = fmaxf((a2 + (float)la.h[2] * iS) + (c2 + (float)lb.h[2] * iS), 0.f);
            const float q3 = fmaxf((a3 + (float)la.h[3] * iS) + (c3 + (float)lb.h[3] * iS), 0.f);
            float t0 = q0 * w0.x + q1 * w0.y + q2 * w0.z + q3 * w0.w;
            float t1 = q0 * w1.x + q1 * w1.y + q2 * w1.z + q3 * w1.w;
#pragma unroll
            for (int off = 1; off < 16; off <<= 1) {
                t0 += __shfl_xor(t0, off, 16);
                t1 += __shfl_xor(t1, off, 16);
            }
            const float ge = (t0 + b20 + g0) - (t1 + b21 + g1);
            av = (ge >= 0.f) ? 1.f : 0.f;
        }
        if (j == 0) act[el] = av;
    }
    __syncthreads();

    if (t < EPB) {
        const float a = act[t];
        const size_t e = (size_t)e0 + t;
        out[e]                  = a;
        out[EE + e]             = 1.f - a;
        out[2 * (size_t)EE + e] = 1.f - a;
    }
}

// ---------------------------------------------------------------------------
extern "C" void kernel_launch(void* const* d_in, const int* in_sizes, int n_in,
                              void* d_out, int out_size, void* d_ws, size_t ws_size,
                              hipStream_t stream)
{
    const float* trace  = (const float*)d_in[0];   // (2,100000,128)
    const float* W_lin  = (const float*)d_in[1];   // (256,256)
    const float* W_lin2 = (const float*)d_in[2];   // (128,256)
    const float* W_fc1  = (const float*)d_in[3];   // (64,256)
    const float* b_fc1  = (const float*)d_in[4];   // (64,)
    const float* W_fc2  = (const float*)d_in[5];   // (2,64)
    const float* b_fc2  = (const float*)d_in[6];   // (2,)
    const float* gum    = (const float*)d_in[7];   // (1600000,2)
    const int*   ei     = (const int*)  d_in[8];   // (2,4800000)
    float*       out    = (float*)d_out;           // (4800000,)

    // Workspace (154 MB, SAME footprint as before):
    // [hpl 102.4MB][pH 25.6MB][pL 25.6MB][weight planes 0.46MB].
    // gemm23 reads hpl + weights, writes pH/pL — all regions disjoint.
    char* ws = (char*)d_ws;
    unsigned*       hpl = (unsigned*)ws;
    unsigned short* pH  = (unsigned short*)(ws + (size_t)NN * 256 * 4);
    unsigned short* pL  = (unsigned short*)(ws + (size_t)NN * 256 * 4 + (size_t)NN * 128 * 2);
    unsigned*       W1i = (unsigned*)(ws + (size_t)NN * 256 * 4 + (size_t)NN * 128 * 4);
    unsigned*       W2i = W1i + 65536;
    unsigned*       W3i = W2i + 32768;

    // Split weights into fp16 hi/lo interleaved planes.
    prep_w<<<448, 256, 0, stream>>>(W_lin, W_lin2, W_fc1, W1i, W2i, W3i);

    const int mB = (NN + 127) / 128;   // 782

    // h = relu(x @ W_lin^T), stored split (R5-verified kernel)
    gemm_mfma<0, 256><<<dim3(mB, 2), 256, 0, stream>>>(trace, W1i, hpl, NN, 256);
    // fused: m = normalize(h @ W_lin2^T); p = W3 . m (+bias), split pH/pL
    gemm23<<<mB, 256, 0, stream>>>(hpl, W2i, W3i, b_fc1, pH, pL, NN);
    // per-edge score + hard mask (fp16 fast path, certified split fallback)
    edge_k<<<EE / EPB, 256, 0, stream>>>(pH, pL, ei, gum, W_fc2, b_fc2, out);
}